// Round 6
// baseline (378.420 us; speedup 1.0000x reference)
//
#include <hip/hip_runtime.h>

typedef __attribute__((ext_vector_type(8))) short short8;
typedef __attribute__((ext_vector_type(4))) float floatx4;
typedef unsigned short u16;
typedef unsigned int u32;
typedef unsigned long long u64;

#define KMAXN 32

__device__ __forceinline__ u16 f2b(float f) {
    unsigned u = __builtin_bit_cast(unsigned, f);
    u += 0x7FFFu + ((u >> 16) & 1u);   // RNE (finite values only)
    return (u16)(u >> 16);
}
__device__ __forceinline__ float silu_f(float x) {
    return x / (1.f + __expf(-x));
}

// ---------------------------------------------------------------------------
// k_init: (a) weights f32 -> bf16 transposed (WbT2 k-rows permuted to
// i = d*16 + rbf); (b) zero the NT privatized u32 winner tables and xb's
// sentinel zero-row (row N).
// ---------------------------------------------------------------------------
__global__ __launch_bounds__(256) void k_init(const float* __restrict__ Wd,
                                              const float* __restrict__ Wb,
                                              const float* __restrict__ Wu,
                                              u16* __restrict__ WdT,    // [64][256]
                                              u16* __restrict__ WbT2,   // [64][1024] permuted-k
                                              u16* __restrict__ WuT,    // [256][64]
                                              u32* __restrict__ win32,  // [nt][nslots]
                                              u16* __restrict__ xb,     // [(N+1)][64]
                                              int nslots, int nt) {
    long idx = (long)blockIdx.x * 256 + threadIdx.x;
    if (idx < 16384) {                       // WdT[n][k] = Wd[k*64+n]
        WdT[idx] = f2b(Wd[(idx & 255) * 64 + (idx >> 8)]);
    } else if (idx < 81920) {                // WbT2[n][d*16+rbf] = Wb[(rbf*64+d)*64+n]
        int i = (int)idx - 16384;
        int n = i >> 10, s = i & 1023;
        int d = s >> 4, rbf = s & 15;
        WbT2[i] = f2b(Wb[(rbf * 64 + d) * 64 + n]);
    } else if (idx < 98304) {                // WuT[n][k] = Wu[k*256+n]
        int i = (int)idx - 81920;
        WuT[i] = f2b(Wu[(i & 63) * 256 + (i >> 6)]);
    } else {
        long z = idx - 98304;                // zero winner tables: uint4 = 4 slots
        long ztot = (long)nt * nslots / 4;
        uint4 zero = {0, 0, 0, 0};
        if (z < ztot) {
            reinterpret_cast<uint4*>(win32)[z] = zero;
            if (z < 8) {                     // zero sentinel row xb[N][0..63]
                long N = nslots / KMAXN;
                reinterpret_cast<uint4*>(xb + N * 64)[z] = zero;
            }
        }
    }
}

// ---------------------------------------------------------------------------
// k_prep: fused down-projection (blocks [0,DOWN)) + winner scatter
// (blocks [DOWN,DOWN+WIN)).  Scatter: atomicMax of (e+1) into the table
// selected by (block & tmask) — with round-robin block->XCD dispatch each
// table is written by (mostly) one XCD, keeping its lines XCD-L2-local.
// max over e+1 == numpy last-write-wins.  Correctness does not depend on
// the block->XCD mapping (atomics stay device-scope).
// ---------------------------------------------------------------------------
__global__ __launch_bounds__(256) void k_prep(const float* __restrict__ h,
                                              const u16*   __restrict__ WdT,
                                              u16*         __restrict__ xb,
                                              const int*   __restrict__ esrc,
                                              const int*   __restrict__ edst,
                                              const int*   __restrict__ tni,
                                              u32*         __restrict__ win32,
                                              int E, int DOWN, int nslots, int tmask) {
    const int tid = threadIdx.x;
    if ((int)blockIdx.x >= DOWN) {
        int wb = blockIdx.x - DOWN;
        int e = wb * 256 + tid;
        if (e < E) {
            size_t tbase = (size_t)(wb & tmask) * nslots;
            atomicMax(&win32[tbase + (size_t)edst[e] * KMAXN + tni[e]], (u32)(e + 1));
        }
        return;
    }
    // ---- down role: xb = silu(h @ Wd) as bf16, 16 atoms/block ----
    const int wave = tid >> 6;
    const int lane = tid & 63;
    const int m = lane & 15;
    const int q = lane >> 4;
    const long atom0 = (long)blockIdx.x * 16;

    const float* arow = h + (atom0 + m) * 256 + q * 8;
    const u16* brow = WdT + (wave * 16 + m) * 256 + q * 8;
    floatx4 acc = {0.f, 0.f, 0.f, 0.f};
#pragma unroll
    for (int kk = 0; kk < 8; ++kk) {
        float4 f0 = *reinterpret_cast<const float4*>(arow + kk * 32);
        float4 f1 = *reinterpret_cast<const float4*>(arow + kk * 32 + 4);
        short8 a;
        a[0] = (short)f2b(f0.x); a[1] = (short)f2b(f0.y);
        a[2] = (short)f2b(f0.z); a[3] = (short)f2b(f0.w);
        a[4] = (short)f2b(f1.x); a[5] = (short)f2b(f1.y);
        a[6] = (short)f2b(f1.z); a[7] = (short)f2b(f1.w);
        short8 b = *reinterpret_cast<const short8*>(brow + kk * 32);
        acc = __builtin_amdgcn_mfma_f32_16x16x32_bf16(a, b, acc, 0, 0, 0);
    }
#pragma unroll
    for (int r = 0; r < 4; ++r) {
        xb[(atom0 + q * 4 + r) * 64 + wave * 16 + m] = f2b(silu_f(acc[r]));
    }
}

// ---------------------------------------------------------------------------
// k_merge: reduce the NT privatized tables (max over e+1), resolve the
// winning edge to its source atom (or sentinel N for empty), and write the
// final src table IN PLACE over table 0.  Coalesced per-table reads.
// ---------------------------------------------------------------------------
__global__ __launch_bounds__(256) void k_merge(u32* __restrict__ win32,
                                               const int* __restrict__ esrc,
                                               int nslots, int nt, int N) {
    int s = blockIdx.x * 256 + threadIdx.x;
    if (s >= nslots) return;
    u32 w = win32[s];
    for (int t = 1; t < nt; ++t) {
        u32 v = win32[(size_t)t * nslots + s];
        w = v > w ? v : w;
    }
    win32[s] = w ? (u32)esrc[w - 1] : (u32)N;
}

// ---------------------------------------------------------------------------
// k_fused v6: einsum('nrk,nkd', rad, x2) -> @Wb*scale -> silu(@Wu)
// Identical to v5 (passed, 109.5us) except Phase A reads the PRE-RESOLVED
// src32 table (2x uint4 per atom-row) instead of decoding win64 pairs.
// ---------------------------------------------------------------------------
#define T_STRIDE 1032   // t row: 1024 + 8 pad (2064 B, 16B-aligned)

__global__ __launch_bounds__(256, 2) void k_fused(
        const float* __restrict__ rad,     // [N][16][32] f32
        const u16*   __restrict__ xb,      // [(N+1)][64] bf16 (row N = zeros)
        const u32*   __restrict__ src32,   // [N*32]: source atom or N (empty)
        const u16*   __restrict__ WbT2,    // [64][1024] bf16, permuted k
        const u16*   __restrict__ WuT,     // [256][64] bf16
        const float* __restrict__ scale_p, // [1]
        float* __restrict__ out) {         // [N][256] f32
    __shared__ alignas(16) u16 t2[16][T_STRIDE];       // 33.0 KB
    __shared__ alignas(16) u16 c2_lds[16][72];         //  2.3 KB

    const int tid  = threadIdx.x;
    const int wave = tid >> 6;
    const int lane = tid & 63;
    const int m = lane & 15;
    const int q = lane >> 4;
    const long atom0 = (long)blockIdx.x * 16;
    const long nbase = atom0 + wave * 4;

    // ---- Phase A load batch ----
    // 1) pre-resolved srcs: 4 atoms x 2 uint4 (8 slots each)
    uint4 sv[4][2];
#pragma unroll
    for (int a = 0; a < 4; ++a) {
        const uint4* sp = reinterpret_cast<const uint4*>(src32 + (nbase + a) * KMAXN + q * 8);
        sv[a][0] = sp[0];
        sv[a][1] = sp[1];
    }
    // 2) rad: 4 atoms x 2 float4
    float4 rf[4][2];
#pragma unroll
    for (int a = 0; a < 4; ++a) {
        const float* rrow = rad + (nbase + a) * 512 + m * 32 + q * 8;
        rf[a][0] = *reinterpret_cast<const float4*>(rrow);
        rf[a][1] = *reinterpret_cast<const float4*>(rrow + 4);
    }
    // 3) element offsets into xb
    u32 off[4][8];
#pragma unroll
    for (int a = 0; a < 4; ++a) {
        off[a][0] = sv[a][0].x * 64u + (u32)m;
        off[a][1] = sv[a][0].y * 64u + (u32)m;
        off[a][2] = sv[a][0].z * 64u + (u32)m;
        off[a][3] = sv[a][0].w * 64u + (u32)m;
        off[a][4] = sv[a][1].x * 64u + (u32)m;
        off[a][5] = sv[a][1].y * 64u + (u32)m;
        off[a][6] = sv[a][1].z * 64u + (u32)m;
        off[a][7] = sv[a][1].w * 64u + (u32)m;
    }
    // 4) issue the 128 transposed gathers into registers (static indices)
    u32 gv[4][8][4];   // [atom][k-slot j][d-block c]
#pragma unroll
    for (int a = 0; a < 4; ++a) {
#pragma unroll
        for (int j = 0; j < 8; ++j) {
            const u16* p = xb + off[a][j];
#pragma unroll
            for (int c = 0; c < 4; ++c) {
                gv[a][j][c] = (u32)p[c * 16];
            }
        }
    }
    // 5) convert rad to bf16 A-fragments (overlaps with gather latency)
    short8 ra[4];
#pragma unroll
    for (int a = 0; a < 4; ++a) {
        ra[a][0] = (short)f2b(rf[a][0].x); ra[a][1] = (short)f2b(rf[a][0].y);
        ra[a][2] = (short)f2b(rf[a][0].z); ra[a][3] = (short)f2b(rf[a][0].w);
        ra[a][4] = (short)f2b(rf[a][1].x); ra[a][5] = (short)f2b(rf[a][1].y);
        ra[a][6] = (short)f2b(rf[a][1].z); ra[a][7] = (short)f2b(rf[a][1].w);
    }

    // ---- Phase A compute: t[a] = rad[a] @ x2[a] ----
#pragma unroll
    for (int a = 0; a < 4; ++a) {
#pragma unroll
        for (int c = 0; c < 4; ++c) {
            union { u32 u[4]; short8 s; } bx;
            bx.u[0] = (gv[a][0][c] & 0xffffu) | (gv[a][1][c] << 16);
            bx.u[1] = (gv[a][2][c] & 0xffffu) | (gv[a][3][c] << 16);
            bx.u[2] = (gv[a][4][c] & 0xffffu) | (gv[a][5][c] << 16);
            bx.u[3] = (gv[a][6][c] & 0xffffu) | (gv[a][7][c] << 16);
            floatx4 tz = {0.f, 0.f, 0.f, 0.f};
            tz = __builtin_amdgcn_mfma_f32_16x16x32_bf16(ra[a], bx.s, tz, 0, 0, 0);
            // pack 4 consecutive rbf (q*4+r) of d-column c*16+m -> one b64
            u32 lo = (u32)f2b(tz[0]) | ((u32)f2b(tz[1]) << 16);
            u32 hi = (u32)f2b(tz[2]) | ((u32)f2b(tz[3]) << 16);
            u64 val = (u64)lo | ((u64)hi << 32);
            *reinterpret_cast<u64*>(&t2[wave * 4 + a][(c * 16 + m) * 16 + q * 4]) = val;
        }
    }
    __syncthreads();   // t2 crosses waves below

    // ---- Phase B: C2[16][64] = t @ Wb (both in permuted-k order), * scale ----
    floatx4 c2 = {0.f, 0.f, 0.f, 0.f};
    const u16* wbrow = WbT2 + (wave * 16 + m) * 1024 + q * 8;
#pragma unroll 4
    for (int kk = 0; kk < 32; ++kk) {
        short8 af = *reinterpret_cast<const short8*>(&t2[m][kk * 32 + q * 8]);
        short8 bf = *reinterpret_cast<const short8*>(wbrow + kk * 32);
        c2 = __builtin_amdgcn_mfma_f32_16x16x32_bf16(af, bf, c2, 0, 0, 0);
    }
    {
        float sc = scale_p[0];
#pragma unroll
        for (int r = 0; r < 4; ++r) {
            c2_lds[q * 4 + r][wave * 16 + m] = f2b(c2[r] * sc);
        }
    }
    __syncthreads();

    // ---- Phase C: out = silu(C2 @ Wu); wave w -> cols [64w, 64w+64) ----
#pragma unroll
    for (int tt = 0; tt < 4; ++tt) {
        floatx4 acc = {0.f, 0.f, 0.f, 0.f};
        const u16* wurow = WuT + (wave * 64 + tt * 16 + m) * 64 + q * 8;
#pragma unroll
        for (int ks = 0; ks < 2; ++ks) {
            short8 af = *reinterpret_cast<const short8*>(&c2_lds[m][ks * 32 + q * 8]);
            short8 bf = *reinterpret_cast<const short8*>(wurow + ks * 32);
            acc = __builtin_amdgcn_mfma_f32_16x16x32_bf16(af, bf, acc, 0, 0, 0);
        }
#pragma unroll
        for (int r = 0; r < 4; ++r) {
            out[(atom0 + q * 4 + r) * 256 + wave * 64 + tt * 16 + m] = silu_f(acc[r]);
        }
    }
}

// ---------------------------------------------------------------------------
extern "C" void kernel_launch(void* const* d_in, const int* in_sizes, int n_in,
                              void* d_out, int out_size, void* d_ws, size_t ws_size,
                              hipStream_t stream) {
    const float* h     = (const float*)d_in[0];
    const float* rad   = (const float*)d_in[1];
    const int*   eidx  = (const int*)d_in[2];   // [2][E]: row0 = src, row1 = dst
    const int*   tni   = (const int*)d_in[3];
    const float* Wd    = (const float*)d_in[4];
    const float* Wb    = (const float*)d_in[5];
    const float* Wu    = (const float*)d_in[6];
    const float* scale = (const float*)d_in[7];
    float* out         = (float*)d_out;

    const int E = in_sizes[3];            // 1,600,000
    const int N = in_sizes[0] / 256;      // 50,000
    const int nslots = N * KMAXN;

    // Workspace: xb bf16 [(N+1)*64] | win32 u32 [NT][nslots] | WdT | WbT2 | WuT
    const size_t xb_bytes = (size_t)(N + 1) * 64 * sizeof(u16);   // ~6.4 MB
    const size_t w_bytes  = (16384 + 65536 + 16384) * sizeof(u16);
    size_t need8 = xb_bytes + (size_t)8 * nslots * sizeof(u32) + w_bytes;  // ~57.8 MB
    const int NT = (ws_size >= need8) ? 8 : 1;     // fallback: single table

    u16* xb = (u16*)d_ws;
    size_t off = xb_bytes;
    u32* win32 = (u32*)((char*)d_ws + off);
    off += (size_t)NT * nslots * sizeof(u32);
    u16* WdT  = (u16*)((char*)d_ws + off);  off += 16384 * 2;
    u16* WbT2 = (u16*)((char*)d_ws + off);  off += 65536 * 2;
    u16* WuT  = (u16*)((char*)d_ws + off);

    const int DOWN = N / 16;                       // 3125
    const int WIN  = (E + 255) / 256;              // 6250
    const int INIT = 384 + ((long)NT * nslots / 4 + 255) / 256;
    const int MERGE = (nslots + 255) / 256;        // 6250

    k_init<<<INIT, 256, 0, stream>>>(Wd, Wb, Wu, WdT, WbT2, WuT, win32, xb, nslots, NT);
    k_prep<<<DOWN + WIN, 256, 0, stream>>>(h, WdT, xb, eidx, eidx + E, tni, win32,
                                           E, DOWN, nslots, NT - 1);
    k_merge<<<MERGE, 256, 0, stream>>>(win32, eidx, nslots, NT, N);
    k_fused<<<DOWN, 256, 0, stream>>>(rad, xb, win32, WbT2, WuT, scale, out);
}